// Round 11
// baseline (16354.956 us; speedup 1.0000x reference)
//
#include <hip/hip_runtime.h>
#include <stdint.h>

#define B_   128
#define T_   64
#define V_   1024
#define TS_  64
#define H_   512
#define K_   (V_ + TS_)   // 1088

// ---------------------------------------------------------------------------
// Fused time-aware GRU scan, round 11.
//
// 64 WGs x 256 threads = 256 fully independent waves (no barriers, no LDS).
// Wave q = blk*4+w owns h[2q],h[2q+1]. Exchange = r9/r10's packed tagged u64
// per wave: (ver<<32)|(bf16(hj1)<<16)|bf16(hj0), agent-relaxed atomics.
//
// Ledger: traffic knobs dead (r7 -7%, r8 -89%, r9 +4%); serial-cycle cuts
// live (r10 DPP reduction + early sweep issue: +16%). r11 removes the last
// handoff hop and halves detect granularity:
//   1. ALL-WAVE DIRECT POLL: every wave sweeps the 256 words itself (4
//      loads/lane) -- no leader, no LDS broadcast, no __syncthreads. The
//      lane<->h mismatch is fixed by PERMUTING the h-side weight k-mapping
//      at init: lane L holds words L+64u = pairs k = 2L+128u+s; weights
//      are loaded with the same mapping (sum over k is order-free).
//   2. TWO-DEEP PIPELINED POLL: two sweeps in flight; check the older with
//      vmcnt(4) while the younger flies -> detect granularity ~halves.
//   3. keep r10: first sweep issued before the x-dots (overlap), DPP wave
//      reduction, wave-uniform gates.
//
// Safety: tag v+1 is stored by wave q only after q observed ALL tags v;
// any tag v postdates that wave's reads of slot (v+1)&1 for v-1 => no
// overwrite race. Per-wave bounded-spin watchdog (2^21): a dead wave
// free-runs but keeps publishing correctly-tagged data => no one blocks;
// protocol bugs end as fast absmax-fails, not dead containers.
//
// Masked steps (t >= lens[b]) skipped; chain = sum(lens) ~ 4032 steps.
// Workspace: 2 slots x 256 x u64 = 4KB. Poison tag 0xAAAAAAAA != any ver.
// ---------------------------------------------------------------------------

__device__ __forceinline__ float sigmoidf_(float x) {
    return 1.0f / (1.0f + __expf(-x));
}
__device__ __forceinline__ float tanhf_(float x) {
    x = fminf(fmaxf(x, -15.0f), 15.0f);
    const float e = __expf(2.0f * x);
    return (e - 1.0f) / (e + 1.0f);
}
__device__ __forceinline__ uint32_t bf16_rn_(float f) {
    uint32_t u = __float_as_uint(f);
    u += 0x7FFFu + ((u >> 16) & 1u);   // round-to-nearest-even
    return u >> 16;
}
__device__ __forceinline__ float bf16_to_f32_(uint32_t b) {
    return __uint_as_float(b << 16);
}

// GCN DPP full-wave sum (r10-verified): row_shr 1/2/4/8, row_bcast 15/31,
// result in lane 63, readlane-broadcast.
template <int CTRL, int RM, int BM>
__device__ __forceinline__ float dpp_add_(float a) {
    const int x = __builtin_amdgcn_update_dpp(
        0, __float_as_int(a), CTRL, RM, BM, true);
    return a + __int_as_float(x);
}
__device__ __forceinline__ float wave_sum_(float a) {
    a = dpp_add_<0x111, 0xF, 0xF>(a);
    a = dpp_add_<0x112, 0xF, 0xF>(a);
    a = dpp_add_<0x114, 0xF, 0xE>(a);
    a = dpp_add_<0x118, 0xF, 0xC>(a);
    a = dpp_add_<0x142, 0xA, 0xF>(a);
    a = dpp_add_<0x143, 0xC, 0xF>(a);
    return __int_as_float(__builtin_amdgcn_readlane(__float_as_int(a), 63));
}

#define LOADW(d0, d1, d2, d3)                                                 \
    do {                                                                      \
        d0 = __hip_atomic_load(&src[lane],       __ATOMIC_RELAXED,            \
                               __HIP_MEMORY_SCOPE_AGENT);                     \
        d1 = __hip_atomic_load(&src[lane + 64],  __ATOMIC_RELAXED,            \
                               __HIP_MEMORY_SCOPE_AGENT);                     \
        d2 = __hip_atomic_load(&src[lane + 128], __ATOMIC_RELAXED,            \
                               __HIP_MEMORY_SCOPE_AGENT);                     \
        d3 = __hip_atomic_load(&src[lane + 192], __ATOMIC_RELAXED,            \
                               __HIP_MEMORY_SCOPE_AGENT);                     \
    } while (0)

#define TAGOK4(d0, d1, d2, d3)                                                \
    (((uint32_t)((d0) >> 32) == ver) && ((uint32_t)((d1) >> 32) == ver) &&    \
     ((uint32_t)((d2) >> 32) == ver) && ((uint32_t)((d3) >> 32) == ver))

__global__ __launch_bounds__(256, 1) void gru_fused(
    const float* __restrict__ visit_emb, const float* __restrict__ intervals,
    const float* __restrict__ W_time, const float* __restrict__ b_time,
    const float* __restrict__ W_ih, const float* __restrict__ W_hh,
    const float* __restrict__ b_ih, const float* __restrict__ b_hh,
    const int* __restrict__ lens,
    uint64_t* h_buf /* [2 slot][256] tagged packed */,
    float* __restrict__ out)
{
    const int lane = threadIdx.x & 63;
    const int wave = threadIdx.x >> 6;        // 0..3
    const int q    = blockIdx.x * 4 + wave;   // 0..255 global wave id
    const int j0   = q * 2;
    const int j1   = j0 + 1;

    // ---- h-side W_hh rows in PERMUTED k-order: v=2u+s <-> k=2*lane+128u+s
    float wr0[8], wr1[8], wz0[8], wz1[8], wn0[8], wn1[8];
    #pragma unroll
    for (int u = 0; u < 4; ++u)
        #pragma unroll
        for (int s = 0; s < 2; ++s) {
            const int k = 2 * lane + 128 * u + s;
            const int v = 2 * u + s;
            wr0[v] = W_hh[(size_t)j0 * H_ + k];
            wr1[v] = W_hh[(size_t)j1 * H_ + k];
            wz0[v] = W_hh[(size_t)(H_ + j0) * H_ + k];
            wz1[v] = W_hh[(size_t)(H_ + j1) * H_ + k];
            wn0[v] = W_hh[(size_t)(2 * H_ + j0) * H_ + k];
            wn1[v] = W_hh[(size_t)(2 * H_ + j1) * H_ + k];
        }
    // ---- W_ih rows (unpermuted): u<16 visit part, u==16 time part -------
    float ir0[17], ir1[17], iz0[17], iz1[17], in0[17], in1[17];
    #pragma unroll
    for (int u = 0; u < 16; ++u) {
        const int k = lane + 64 * u;
        ir0[u] = W_ih[(size_t)j0 * K_ + k];
        ir1[u] = W_ih[(size_t)j1 * K_ + k];
        iz0[u] = W_ih[(size_t)(H_ + j0) * K_ + k];
        iz1[u] = W_ih[(size_t)(H_ + j1) * K_ + k];
        in0[u] = W_ih[(size_t)(2 * H_ + j0) * K_ + k];
        in1[u] = W_ih[(size_t)(2 * H_ + j1) * K_ + k];
    }
    ir0[16] = W_ih[(size_t)j0 * K_ + V_ + lane];
    ir1[16] = W_ih[(size_t)j1 * K_ + V_ + lane];
    iz0[16] = W_ih[(size_t)(H_ + j0) * K_ + V_ + lane];
    iz1[16] = W_ih[(size_t)(H_ + j1) * K_ + V_ + lane];
    in0[16] = W_ih[(size_t)(2 * H_ + j0) * K_ + V_ + lane];
    in1[16] = W_ih[(size_t)(2 * H_ + j1) * K_ + V_ + lane];

    const float wt = W_time[lane];
    const float bt = b_time[lane];

    const float bir0 = b_ih[j0],          bir1 = b_ih[j1];
    const float biz0 = b_ih[H_ + j0],     biz1 = b_ih[H_ + j1];
    const float bin0 = b_ih[2 * H_ + j0], bin1 = b_ih[2 * H_ + j1];
    const float bhr0 = b_hh[j0],          bhr1 = b_hh[j1];
    const float bhz0 = b_hh[H_ + j0],     bhz1 = b_hh[H_ + j1];
    const float bhn0 = b_hh[2 * H_ + j0], bhn1 = b_hh[2 * H_ + j1];

    float hj0 = 0.0f, hj1 = 0.0f;             // wave-uniform state
    uint32_t ver  = 1;    // ver 1 == initial zero state, lives in slot 1
    uint32_t dead = 0;    // per-wave watchdog state (wave-uniform)

    if (lane == 0)
        __hip_atomic_store(&h_buf[(ver & 1) * 256 + q], (uint64_t)ver << 32,
                           __ATOMIC_RELAXED, __HIP_MEMORY_SCOPE_AGENT);

    float xv[16];
    float iv = 0.0f;

    for (int b = 0; b < B_; ++b) {
        const int L = lens[b];
        if (L > 0) {
            iv = intervals[b * T_];
            const float* vrow = visit_emb + (size_t)(b * T_) * V_;
            #pragma unroll
            for (int u = 0; u < 16; ++u) xv[u] = vrow[lane + 64 * u];
        }
        for (int t = 0; t < L; ++t) {
            const uint64_t* src = h_buf + (ver & 1) * 256;
            uint64_t a0, a1, a2, a3, c0, c1, c2, c3;

            // ---- sweep A issued first (overlaps x-dots) -----------------
            LOADW(a0, a1, a2, a3);

            // ---- x-side dots (h-independent) ----------------------------
            const float xt = fmaf(iv, wt, bt);
            float ar0 = ir0[16] * xt, ar1 = ir1[16] * xt;
            float az0 = iz0[16] * xt, az1 = iz1[16] * xt;
            float xn0 = in0[16] * xt, xn1 = in1[16] * xt;
            #pragma unroll
            for (int u = 0; u < 16; ++u) {
                ar0 = fmaf(ir0[u], xv[u], ar0);
                ar1 = fmaf(ir1[u], xv[u], ar1);
                az0 = fmaf(iz0[u], xv[u], az0);
                az1 = fmaf(iz1[u], xv[u], az1);
                xn0 = fmaf(in0[u], xv[u], xn0);
                xn1 = fmaf(in1[u], xv[u], xn1);
            }
            // ---- prefetch next step's x row -----------------------------
            if (t + 1 < L) {
                iv = intervals[b * T_ + t + 1];
                const float* vrow = visit_emb + (size_t)(b * T_ + t + 1) * V_;
                #pragma unroll
                for (int u = 0; u < 16; ++u) xv[u] = vrow[lane + 64 * u];
            }

            // ---- two-deep pipelined detect ------------------------------
            uint64_t w0, w1, w2, w3;
            if (!dead) {
                LOADW(c0, c1, c2, c3);           // sweep B in flight
                uint32_t tries = 0;
                for (;;) {
                    if (__all(TAGOK4(a0, a1, a2, a3))) {
                        w0 = a0; w1 = a1; w2 = a2; w3 = a3; break;
                    }
                    LOADW(a0, a1, a2, a3);       // reissue A
                    if (++tries > (1u << 21)) {  // watchdog -> free-run
                        dead = 1;
                        w0 = c0; w1 = c1; w2 = c2; w3 = c3; break;
                    }
                    if (__all(TAGOK4(c0, c1, c2, c3))) {
                        w0 = c0; w1 = c1; w2 = c2; w3 = c3; break;
                    }
                    LOADW(c0, c1, c2, c3);       // reissue B
                }
            } else {
                w0 = a0; w1 = a1; w2 = a2; w3 = a3;   // free-run
            }

            // ---- unpack permuted h (v=2u+s) -----------------------------
            float h[8];
            {
                const uint32_t d0 = (uint32_t)w0, d1 = (uint32_t)w1;
                const uint32_t d2 = (uint32_t)w2, d3 = (uint32_t)w3;
                h[0] = bf16_to_f32_(d0 & 0xFFFFu); h[1] = bf16_to_f32_(d0 >> 16);
                h[2] = bf16_to_f32_(d1 & 0xFFFFu); h[3] = bf16_to_f32_(d1 >> 16);
                h[4] = bf16_to_f32_(d2 & 0xFFFFu); h[5] = bf16_to_f32_(d2 >> 16);
                h[6] = bf16_to_f32_(d3 & 0xFFFFu); h[7] = bf16_to_f32_(d3 >> 16);
            }

            // ---- h-side dots (permuted weights match unpack order) ------
            float hn0 = 0.0f, hn1 = 0.0f;
            #pragma unroll
            for (int v = 0; v < 8; ++v) {
                ar0 = fmaf(wr0[v], h[v], ar0);
                ar1 = fmaf(wr1[v], h[v], ar1);
                az0 = fmaf(wz0[v], h[v], az0);
                az1 = fmaf(wz1[v], h[v], az1);
                hn0 = fmaf(wn0[v], h[v], hn0);
                hn1 = fmaf(wn1[v], h[v], hn1);
            }

            // ---- 8 pipelined DPP wave sums ------------------------------
            const float sr0 = wave_sum_(ar0), sr1 = wave_sum_(ar1);
            const float sz0 = wave_sum_(az0), sz1 = wave_sum_(az1);
            const float sx0 = wave_sum_(xn0), sx1 = wave_sum_(xn1);
            const float sh0 = wave_sum_(hn0), sh1 = wave_sum_(hn1);

            // ---- gates & recurrence (wave-uniform) ----------------------
            const float r0 = sigmoidf_(sr0 + bir0 + bhr0);
            const float r1 = sigmoidf_(sr1 + bir1 + bhr1);
            const float z0 = sigmoidf_(sz0 + biz0 + bhz0);
            const float z1 = sigmoidf_(sz1 + biz1 + bhz1);
            const float n0 = tanhf_(sx0 + bin0 + r0 * (sh0 + bhn0));
            const float n1 = tanhf_(sx1 + bin1 + r1 * (sh1 + bhn1));
            hj0 = (1.0f - z0) * n0 + z0 * hj0;
            hj1 = (1.0f - z1) * n1 + z1 * hj1;

            // ---- publish ONE tagged packed word per wave ----------------
            ++ver;
            if (lane == 0) {
                const uint32_t packed = bf16_rn_(hj0) | (bf16_rn_(hj1) << 16);
                __hip_atomic_store(&h_buf[(ver & 1) * 256 + q],
                    ((uint64_t)ver << 32) | (uint64_t)packed,
                    __ATOMIC_RELAXED, __HIP_MEMORY_SCOPE_AGENT);
            }
        }
        // out[b] = h after sample b's (possibly empty) segment
        if (lane < 2) out[b * H_ + j0 + lane] = (lane == 0) ? hj0 : hj1;
    }
}

// ---------------------------------------------------------------------------
extern "C" void kernel_launch(void* const* d_in, const int* in_sizes, int n_in,
                              void* d_out, int out_size, void* d_ws, size_t ws_size,
                              hipStream_t stream)
{
    const float* visit_emb = (const float*)d_in[0];
    const float* intervals = (const float*)d_in[1];
    const float* W_time    = (const float*)d_in[2];
    const float* b_time    = (const float*)d_in[3];
    const float* W_ih      = (const float*)d_in[4];
    const float* W_hh      = (const float*)d_in[5];
    const float* b_ih      = (const float*)d_in[6];
    const float* b_hh      = (const float*)d_in[7];
    const int*   lens      = (const int*)d_in[8];
    float*       out       = (float*)d_out;

    // workspace: packed tagged h exchange (2 x 256 x u64 = 4 KiB)
    uint64_t* h_buf = (uint64_t*)d_ws;

    gru_fused<<<64, 256, 0, stream>>>(visit_emb, intervals, W_time, b_time,
                                      W_ih, W_hh, b_ih, b_hh, lens, h_buf, out);
}

// Round 12
// 7267.666 us; speedup vs baseline: 2.2504x; 2.2504x over previous
//
#include <hip/hip_runtime.h>
#include <stdint.h>

#define B_   128
#define T_   64
#define V_   1024
#define TS_  64
#define H_   512
#define K_   (V_ + TS_)   // 1088

// ---------------------------------------------------------------------------
// Fused time-aware GRU scan, round 12 = round 10 workers (7.42ms best)
// + 192 HEATER blocks to hold the DPM clock up.
//
// Ledger: traffic knobs dead at 64 pollers (r7 -7%, r8 -89%, r9 +4%);
// 256 pollers catastrophic (r2 11.2ms, r11 16.4ms -- contention knee is
// between 64 and 256). Serial-cycle cuts work (r10 +16%). Residual: r10's
// chain should cost ~1.0us at 2.4GHz but measures 1.84us => effective
// clock ~1.3GHz (governor sees 9% VALU / 0.2% HBM; first dispatch is 5x
// slower while clocks ramp). r12 keeps 192 otherwise-idle CUs busy with
// pure-VALU heater blocks -> chip VALU ~75% -> governor holds sclk high.
//
// Heaters: 4 independent FMA chains (full VALU issue), check a 'done'
// word every ~256 FMAs (agent-relaxed load, dedicated cache line away
// from h_buf -> no poll interference). Worker wave q==255 sets done=1
// after its last step (all waves are within +-1 step => heaters never
// extend the dispatch). Poison 0xAA..!=1 => no early exit; the watchdog
// guarantees done is eventually stored even under a protocol bug.
//
// Worker structure (r10, unchanged): 64 WGs x 4 waves; wave q owns
// h[2q],h[2q+1]; leader wave polls the packed tagged exchange
// (ver<<32)|(bf16(hj1)<<16)|bf16(hj0), 4 loads/lane over 256 words,
// issued BEFORE the x-dots (overlap), LDS broadcast + 1 barrier; DPP wave
// reduction; wave-uniform gates; 1 tagged store per wave per step.
//
// Workspace: [0,4KB) h_buf, [4KB,+64B) done word, [4224,...) heater sink.
// ---------------------------------------------------------------------------

__device__ __forceinline__ float sigmoidf_(float x) {
    return 1.0f / (1.0f + __expf(-x));
}
__device__ __forceinline__ float tanhf_(float x) {
    x = fminf(fmaxf(x, -15.0f), 15.0f);
    const float e = __expf(2.0f * x);
    return (e - 1.0f) / (e + 1.0f);
}
__device__ __forceinline__ uint32_t bf16_rn_(float f) {
    uint32_t u = __float_as_uint(f);
    u += 0x7FFFu + ((u >> 16) & 1u);   // round-to-nearest-even
    return u >> 16;
}
__device__ __forceinline__ float bf16_to_f32_(uint32_t b) {
    return __uint_as_float(b << 16);
}

// GCN DPP full-wave sum (r10-verified): row_shr 1/2/4/8, row_bcast 15/31,
// result in lane 63, readlane-broadcast.
template <int CTRL, int RM, int BM>
__device__ __forceinline__ float dpp_add_(float a) {
    const int x = __builtin_amdgcn_update_dpp(
        0, __float_as_int(a), CTRL, RM, BM, true);
    return a + __int_as_float(x);
}
__device__ __forceinline__ float wave_sum_(float a) {
    a = dpp_add_<0x111, 0xF, 0xF>(a);
    a = dpp_add_<0x112, 0xF, 0xF>(a);
    a = dpp_add_<0x114, 0xF, 0xE>(a);
    a = dpp_add_<0x118, 0xF, 0xC>(a);
    a = dpp_add_<0x142, 0xA, 0xF>(a);
    a = dpp_add_<0x143, 0xC, 0xF>(a);
    return __int_as_float(__builtin_amdgcn_readlane(__float_as_int(a), 63));
}

__global__ __launch_bounds__(256, 1) void gru_fused(
    const float* __restrict__ visit_emb, const float* __restrict__ intervals,
    const float* __restrict__ W_time, const float* __restrict__ b_time,
    const float* __restrict__ W_ih, const float* __restrict__ W_hh,
    const float* __restrict__ b_ih, const float* __restrict__ b_hh,
    const int* __restrict__ lens,
    uint64_t* h_buf /* [2 slot][256] tagged packed */,
    float* __restrict__ out)
{
    uint32_t* done_w = (uint32_t*)((char*)h_buf + 4096);

    // =================== HEATER BLOCKS (blockIdx >= 64) ==================
    if (blockIdx.x >= 64) {
        float a0 = (float)(blockIdx.x * 256 + threadIdx.x) * 1e-6f + 1.01f;
        float a1 = a0 + 0.1f, a2 = a0 + 0.2f, a3 = a0 + 0.3f;
        const float c = 1.0000001f, d = 1e-7f;
        for (;;) {
            #pragma unroll
            for (int i = 0; i < 64; ++i) {     // 4 indep chains -> full issue
                a0 = fmaf(a0, c, d);
                a1 = fmaf(a1, c, d);
                a2 = fmaf(a2, c, d);
                a3 = fmaf(a3, c, d);
            }
            const uint32_t f = __hip_atomic_load(done_w, __ATOMIC_RELAXED,
                                                 __HIP_MEMORY_SCOPE_AGENT);
            if (f == 1u) break;
        }
        const float s = a0 + a1 + a2 + a3;
        if (s == 1234.56789f && threadIdx.x == 0)   // defeat DCE; never true
            ((float*)((char*)h_buf + 4224))[blockIdx.x] = s;
        return;
    }

    // =================== WORKER BLOCKS (r10 verbatim) ====================
    const int lane = threadIdx.x & 63;
    const int wave = threadIdx.x >> 6;        // 0..3
    const int q    = blockIdx.x * 4 + wave;   // 0..255 global wave id
    const int j0   = q * 2;
    const int j1   = j0 + 1;

    __shared__ float2 hs2[256];               // unpacked h pairs (fp32)
    float* hs = (float*)hs2;                  // alias: hs[512]

    float wr0[8], wr1[8], wz0[8], wz1[8], wn0[8], wn1[8];
    #pragma unroll
    for (int u = 0; u < 8; ++u) {
        const int k = lane + 64 * u;
        wr0[u] = W_hh[(size_t)j0 * H_ + k];
        wr1[u] = W_hh[(size_t)j1 * H_ + k];
        wz0[u] = W_hh[(size_t)(H_ + j0) * H_ + k];
        wz1[u] = W_hh[(size_t)(H_ + j1) * H_ + k];
        wn0[u] = W_hh[(size_t)(2 * H_ + j0) * H_ + k];
        wn1[u] = W_hh[(size_t)(2 * H_ + j1) * H_ + k];
    }
    float ir0[17], ir1[17], iz0[17], iz1[17], in0[17], in1[17];
    #pragma unroll
    for (int u = 0; u < 16; ++u) {
        const int k = lane + 64 * u;
        ir0[u] = W_ih[(size_t)j0 * K_ + k];
        ir1[u] = W_ih[(size_t)j1 * K_ + k];
        iz0[u] = W_ih[(size_t)(H_ + j0) * K_ + k];
        iz1[u] = W_ih[(size_t)(H_ + j1) * K_ + k];
        in0[u] = W_ih[(size_t)(2 * H_ + j0) * K_ + k];
        in1[u] = W_ih[(size_t)(2 * H_ + j1) * K_ + k];
    }
    ir0[16] = W_ih[(size_t)j0 * K_ + V_ + lane];
    ir1[16] = W_ih[(size_t)j1 * K_ + V_ + lane];
    iz0[16] = W_ih[(size_t)(H_ + j0) * K_ + V_ + lane];
    iz1[16] = W_ih[(size_t)(H_ + j1) * K_ + V_ + lane];
    in0[16] = W_ih[(size_t)(2 * H_ + j0) * K_ + V_ + lane];
    in1[16] = W_ih[(size_t)(2 * H_ + j1) * K_ + V_ + lane];

    const float wt = W_time[lane];
    const float bt = b_time[lane];

    const float bir0 = b_ih[j0],          bir1 = b_ih[j1];
    const float biz0 = b_ih[H_ + j0],     biz1 = b_ih[H_ + j1];
    const float bin0 = b_ih[2 * H_ + j0], bin1 = b_ih[2 * H_ + j1];
    const float bhr0 = b_hh[j0],          bhr1 = b_hh[j1];
    const float bhz0 = b_hh[H_ + j0],     bhz1 = b_hh[H_ + j1];
    const float bhn0 = b_hh[2 * H_ + j0], bhn1 = b_hh[2 * H_ + j1];

    float hj0 = 0.0f, hj1 = 0.0f;             // wave-uniform state
    uint32_t ver  = 1;    // ver 1 == initial zero state, lives in slot 1
    uint32_t dead = 0;    // leader watchdog state (wave-uniform)

    if (lane == 0)
        __hip_atomic_store(&h_buf[(ver & 1) * 256 + q], (uint64_t)ver << 32,
                           __ATOMIC_RELAXED, __HIP_MEMORY_SCOPE_AGENT);

    float xv[16];
    float iv = 0.0f;

    for (int b = 0; b < B_; ++b) {
        const int L = lens[b];
        if (L > 0) {
            iv = intervals[b * T_];
            const float* vrow = visit_emb + (size_t)(b * T_) * V_;
            #pragma unroll
            for (int u = 0; u < 16; ++u) xv[u] = vrow[lane + 64 * u];
        }
        for (int t = 0; t < L; ++t) {
            // ---- leader: ISSUE first sweep before x-dots ----------------
            const uint64_t* src = h_buf + (ver & 1) * 256;
            uint64_t w[4];
            if (wave == 0) {
                #pragma unroll
                for (int u = 0; u < 4; ++u)
                    w[u] = __hip_atomic_load(&src[lane + 64 * u],
                                             __ATOMIC_RELAXED,
                                             __HIP_MEMORY_SCOPE_AGENT);
            }

            // ---- x-side dots (h-independent; overlap the sweep) ---------
            const float xt = fmaf(iv, wt, bt);
            float ar0 = ir0[16] * xt, ar1 = ir1[16] * xt;
            float az0 = iz0[16] * xt, az1 = iz1[16] * xt;
            float xn0 = in0[16] * xt, xn1 = in1[16] * xt;
            #pragma unroll
            for (int u = 0; u < 16; ++u) {
                ar0 = fmaf(ir0[u], xv[u], ar0);
                ar1 = fmaf(ir1[u], xv[u], ar1);
                az0 = fmaf(iz0[u], xv[u], az0);
                az1 = fmaf(iz1[u], xv[u], az1);
                xn0 = fmaf(in0[u], xv[u], xn0);
                xn1 = fmaf(in1[u], xv[u], xn1);
            }
            // ---- prefetch next step's x row (in flight across barrier) --
            if (t + 1 < L) {
                iv = intervals[b * T_ + t + 1];
                const float* vrow = visit_emb + (size_t)(b * T_ + t + 1) * V_;
                #pragma unroll
                for (int u = 0; u < 16; ++u) xv[u] = vrow[lane + 64 * u];
            }

            // ---- leader: check tags (waitcnt lands here), retry, LDS ----
            if (wave == 0) {
                if (!dead) {
                    bool ok = true;
                    #pragma unroll
                    for (int u = 0; u < 4; ++u)
                        ok = ok && ((uint32_t)(w[u] >> 32) == ver);
                    uint32_t tries = 0;
                    while (!__all(ok)) {
                        if (++tries > (1u << 21)) { dead = 1; break; }
                        ok = true;
                        #pragma unroll
                        for (int u = 0; u < 4; ++u) {
                            w[u] = __hip_atomic_load(&src[lane + 64 * u],
                                                     __ATOMIC_RELAXED,
                                                     __HIP_MEMORY_SCOPE_AGENT);
                            ok = ok && ((uint32_t)(w[u] >> 32) == ver);
                        }
                    }
                }
                #pragma unroll
                for (int u = 0; u < 4; ++u) {
                    const uint32_t d = (uint32_t)w[u];
                    hs2[lane + 64 * u] =
                        make_float2(bf16_to_f32_(d & 0xFFFFu),
                                    bf16_to_f32_(d >> 16));
                }
            }
            __syncthreads();

            float h[8];
            #pragma unroll
            for (int u = 0; u < 8; ++u) h[u] = hs[lane + 64 * u];

            // ---- h-side dots; r/z merged with x-side, n kept split ------
            float hn0 = 0.0f, hn1 = 0.0f;
            #pragma unroll
            for (int u = 0; u < 8; ++u) {
                ar0 = fmaf(wr0[u], h[u], ar0);
                ar1 = fmaf(wr1[u], h[u], ar1);
                az0 = fmaf(wz0[u], h[u], az0);
                az1 = fmaf(wz1[u], h[u], az1);
                hn0 = fmaf(wn0[u], h[u], hn0);
                hn1 = fmaf(wn1[u], h[u], hn1);
            }

            // ---- 8 pipelined DPP wave sums (VALU, no LDS rounds) --------
            const float sr0 = wave_sum_(ar0), sr1 = wave_sum_(ar1);
            const float sz0 = wave_sum_(az0), sz1 = wave_sum_(az1);
            const float sx0 = wave_sum_(xn0), sx1 = wave_sum_(xn1);
            const float sh0 = wave_sum_(hn0), sh1 = wave_sum_(hn1);

            // ---- gates & recurrence (wave-uniform) ----------------------
            const float r0 = sigmoidf_(sr0 + bir0 + bhr0);
            const float r1 = sigmoidf_(sr1 + bir1 + bhr1);
            const float z0 = sigmoidf_(sz0 + biz0 + bhz0);
            const float z1 = sigmoidf_(sz1 + biz1 + bhz1);
            const float n0 = tanhf_(sx0 + bin0 + r0 * (sh0 + bhn0));
            const float n1 = tanhf_(sx1 + bin1 + r1 * (sh1 + bhn1));
            hj0 = (1.0f - z0) * n0 + z0 * hj0;
            hj1 = (1.0f - z1) * n1 + z1 * hj1;

            // ---- publish ONE tagged packed word per wave ----------------
            ++ver;
            if (lane == 0) {
                const uint32_t packed =
                    bf16_rn_(hj0) | (bf16_rn_(hj1) << 16);
                __hip_atomic_store(&h_buf[(ver & 1) * 256 + q],
                    ((uint64_t)ver << 32) | (uint64_t)packed,
                    __ATOMIC_RELAXED, __HIP_MEMORY_SCOPE_AGENT);
            }
        }
        // out[b] = h after sample b's (possibly empty) segment
        if (lane < 2) out[b * H_ + j0 + lane] = (lane == 0) ? hj0 : hj1;
    }

    // last wave signals the heaters to stop (everyone else is within +-1
    // step of q==255, so heat never extends the dispatch)
    if (q == 255 && lane == 0)
        __hip_atomic_store(done_w, 1u, __ATOMIC_RELAXED,
                           __HIP_MEMORY_SCOPE_AGENT);
}

// ---------------------------------------------------------------------------
extern "C" void kernel_launch(void* const* d_in, const int* in_sizes, int n_in,
                              void* d_out, int out_size, void* d_ws, size_t ws_size,
                              hipStream_t stream)
{
    const float* visit_emb = (const float*)d_in[0];
    const float* intervals = (const float*)d_in[1];
    const float* W_time    = (const float*)d_in[2];
    const float* b_time    = (const float*)d_in[3];
    const float* W_ih      = (const float*)d_in[4];
    const float* W_hh      = (const float*)d_in[5];
    const float* b_ih      = (const float*)d_in[6];
    const float* b_hh      = (const float*)d_in[7];
    const int*   lens      = (const int*)d_in[8];
    float*       out       = (float*)d_out;

    // workspace: [0,4KB) packed tagged h exchange; [4KB) done; [4224) sink
    uint64_t* h_buf = (uint64_t*)d_ws;

    gru_fused<<<256, 256, 0, stream>>>(visit_emb, intervals, W_time, b_time,
                                       W_ih, W_hh, b_ih, b_hh, lens, h_buf, out);
}